// Round 1
// baseline (73789.667 us; speedup 1.0000x reference)
//
#include <hip/hip_runtime.h>
#include <hip/hip_bf16.h>

#define BN 512
#define LN 1024
#define FN 38
#define HN 256
#define ZDN 4
#define FXN 64
#define FZN 32
#define HZN 16

constexpr int BT = 2;            // batch rows per workgroup
constexpr int NWG = BN / BT;     // 256 workgroups
constexpr int NT = 256;          // threads per workgroup

__device__ __forceinline__ float ldw(const float* p) { return *p; }
__device__ __forceinline__ float ldw(const __hip_bfloat16* p) { return __bfloat162float(*p); }

__device__ __forceinline__ float sigmoidf_(float v) { return 1.0f / (1.0f + expf(-v)); }
__device__ __forceinline__ float softplusf_(float v) {
    return fmaxf(v, 0.0f) + log1pf(expf(-fabsf(v)));
}

__global__ void conv_bf16(const float* __restrict__ src, __hip_bfloat16* __restrict__ dst, int n) {
    int i = blockIdx.x * blockDim.x + threadIdx.x;
    if (i < n) dst[i] = __float2bfloat16(src[i]);
}

// WT applies only to the two big GRU weight matrices; small weights stay f32.
template <typename WT>
__global__ __launch_bounds__(NT) void vrnn_main(
    const float* __restrict__ x, const float* __restrict__ eps,
    const float* __restrict__ Wx, const float* __restrict__ bx,
    const float* __restrict__ Wz1, const float* __restrict__ bz1,
    const float* __restrict__ Wz2, const float* __restrict__ bz2,
    const float* __restrict__ Wp_loc, const float* __restrict__ bp_loc,
    const float* __restrict__ Wp_scale, const float* __restrict__ bp_scale,
    const float* __restrict__ Wt_loc, const float* __restrict__ bt_loc,
    const WT* __restrict__ W_ih, const WT* __restrict__ W_hh,
    const float* __restrict__ b_ih, const float* __restrict__ b_hh,
    float* __restrict__ out)
{
    __shared__ float h[2][BT][HN];          // ping-pong hidden state
    __shared__ float xin[BT][FXN + FZN];    // [fx | fz]
    __shared__ float phiraw[BT][2 * ZDN];
    __shared__ float zb[BT][ZDN];
    __shared__ float f1[BT][HZN];

    const int t = threadIdx.x;
    const int wg = blockIdx.x;
    const int b0 = wg * BT;

    for (int i = t; i < 2 * BT * HN; i += NT) ((float*)h)[i] = 0.0f;
    __syncthreads();

    int cur = 0;
#pragma unroll 1
    for (int l = 0; l < LN; ++l) {
        // ---- P1: fx = relu(x @ Wx^T + bx) -> xin[:, 0:64]
        if (t < BT * FXN) {
            int m = t >> 6, e = t & 63;
            float acc = bx[e];
            const float* xr = x + ((size_t)(b0 + m) * LN + l) * FN;
            const float* wr = Wx + e * FN;
#pragma unroll
            for (int f = 0; f < FN; ++f) acc += xr[f] * wr[f];
            xin[m][e] = fmaxf(acc, 0.0f);
        }
        __syncthreads();

        // ---- P2: phi raw = [h, fx] @ Wp^T + bp  (loc c<4, scale c>=4)
        if (t < BT * 2 * ZDN) {
            int m = t >> 3, c = t & 7;
            const float* w = (c < ZDN) ? (Wp_loc + c * (HN + FXN))
                                       : (Wp_scale + (c - ZDN) * (HN + FXN));
            float acc = (c < ZDN) ? bp_loc[c] : bp_scale[c - ZDN];
#pragma unroll 4
            for (int k = 0; k < HN; ++k) acc += h[cur][m][k] * w[k];
#pragma unroll 4
            for (int k = 0; k < FXN; ++k) acc += xin[m][k] * w[HN + k];
            phiraw[m][c] = acc;
        }
        __syncthreads();

        // ---- P2b: z = loc + softplus(scale_raw) * eps
        if (t < BT * ZDN) {
            int m = t >> 2, c = t & 3;
            float e = eps[((size_t)l * BN + b0 + m) * ZDN + c];
            zb[m][c] = phiraw[m][c] + softplusf_(phiraw[m][ZDN + c]) * e;
        }
        __syncthreads();

        // ---- P3: fz1 = relu(z @ Wz1^T + bz1)
        if (t < BT * HZN) {
            int m = t >> 4, j = t & 15;
            float acc = bz1[j];
#pragma unroll
            for (int k = 0; k < ZDN; ++k) acc += zb[m][k] * Wz1[j * ZDN + k];
            f1[m][j] = fmaxf(acc, 0.0f);
        }
        __syncthreads();

        // ---- P4: fz = relu(fz1 @ Wz2^T + bz2) -> xin[:, 64:96]
        if (t < BT * FZN) {
            int m = t >> 5, j = t & 31;
            float acc = bz2[j];
#pragma unroll
            for (int k = 0; k < HZN; ++k) acc += f1[m][k] * Wz2[j * HZN + k];
            xin[m][FXN + j] = fmaxf(acc, 0.0f);
        }
        __syncthreads();

        // ---- P5: x_loc = [fz, h] @ Wt_loc^T + bt_loc  -> out  (no sync needed after)
        if (t < BT * FN) {
            int m = t / FN, f = t % FN;
            float acc = bt_loc[f];
            const float* w = Wt_loc + f * (FZN + HN);
#pragma unroll 4
            for (int k = 0; k < FZN; ++k) acc += xin[m][FXN + k] * w[k];
#pragma unroll 4
            for (int k = 0; k < HN; ++k) acc += h[cur][m][k] * w[FZN + k];
            out[((size_t)(b0 + m) * LN + l) * FN + f] = acc;
        }

        // ---- P6: GRU. thread j owns gate rows j, j+256, j+512.
        {
            const int j = t;
            float air[BT], aiz[BT], ain[BT], ahr[BT], ahz[BT], ahn[BT];
#pragma unroll
            for (int m = 0; m < BT; ++m) {
                air[m] = b_ih[j]; aiz[m] = b_ih[j + HN]; ain[m] = b_ih[j + 2 * HN];
                ahr[m] = b_hh[j]; ahz[m] = b_hh[j + HN]; ahn[m] = b_hh[j + 2 * HN];
            }
            const WT* wir = W_ih + (size_t)j * (FXN + FZN);
            const WT* wiz = wir + (size_t)HN * (FXN + FZN);
            const WT* win = wiz + (size_t)HN * (FXN + FZN);
#pragma unroll 4
            for (int k = 0; k < FXN + FZN; ++k) {
                float wr = ldw(wir + k), wz = ldw(wiz + k), wn = ldw(win + k);
#pragma unroll
                for (int m = 0; m < BT; ++m) {
                    float xv = xin[m][k];
                    air[m] += wr * xv; aiz[m] += wz * xv; ain[m] += wn * xv;
                }
            }
            const WT* whr = W_hh + (size_t)j * HN;
            const WT* whz = whr + (size_t)HN * HN;
            const WT* whn = whz + (size_t)HN * HN;
#pragma unroll 4
            for (int k = 0; k < HN; ++k) {
                float wr = ldw(whr + k), wz = ldw(whz + k), wn = ldw(whn + k);
#pragma unroll
                for (int m = 0; m < BT; ++m) {
                    float hv = h[cur][m][k];
                    ahr[m] += wr * hv; ahz[m] += wz * hv; ahn[m] += wn * hv;
                }
            }
#pragma unroll
            for (int m = 0; m < BT; ++m) {
                float r  = sigmoidf_(air[m] + ahr[m]);
                float zg = sigmoidf_(aiz[m] + ahz[m]);
                float n  = tanhf(ain[m] + r * ahn[m]);
                h[cur ^ 1][m][j] = (1.0f - zg) * n + zg * h[cur][m][j];
            }
        }
        __syncthreads();
        cur ^= 1;
    }
}

extern "C" void kernel_launch(void* const* d_in, const int* in_sizes, int n_in,
                              void* d_out, int out_size, void* d_ws, size_t ws_size,
                              hipStream_t stream) {
    const float* x        = (const float*)d_in[0];
    const float* eps      = (const float*)d_in[1];
    const float* Wx       = (const float*)d_in[2];
    const float* bx       = (const float*)d_in[3];
    const float* Wz1      = (const float*)d_in[4];
    const float* bz1      = (const float*)d_in[5];
    const float* Wz2      = (const float*)d_in[6];
    const float* bz2      = (const float*)d_in[7];
    const float* Wp_loc   = (const float*)d_in[8];
    const float* bp_loc   = (const float*)d_in[9];
    const float* Wp_scale = (const float*)d_in[10];
    const float* bp_scale = (const float*)d_in[11];
    const float* Wt_loc   = (const float*)d_in[12];
    const float* bt_loc   = (const float*)d_in[13];
    // d_in[14], d_in[15] = Wt_scale/bt_scale: unused by the reference output
    const float* W_ih     = (const float*)d_in[16];
    const float* W_hh     = (const float*)d_in[17];
    const float* b_ih     = (const float*)d_in[18];
    const float* b_hh     = (const float*)d_in[19];
    float* out = (float*)d_out;

    const int nWih = 3 * HN * (FXN + FZN);   // 73728
    const int nWhh = 3 * HN * HN;            // 196608
    const size_t need = (size_t)(nWih + nWhh) * sizeof(__hip_bfloat16);

    if (ws_size >= need) {
        __hip_bfloat16* pWih = (__hip_bfloat16*)d_ws;
        __hip_bfloat16* pWhh = pWih + nWih;
        conv_bf16<<<(nWih + 255) / 256, 256, 0, stream>>>(W_ih, pWih, nWih);
        conv_bf16<<<(nWhh + 255) / 256, 256, 0, stream>>>(W_hh, pWhh, nWhh);
        vrnn_main<__hip_bfloat16><<<NWG, NT, 0, stream>>>(
            x, eps, Wx, bx, Wz1, bz1, Wz2, bz2, Wp_loc, bp_loc, Wp_scale, bp_scale,
            Wt_loc, bt_loc, pWih, pWhh, b_ih, b_hh, out);
    } else {
        vrnn_main<float><<<NWG, NT, 0, stream>>>(
            x, eps, Wx, bx, Wz1, bz1, Wz2, bz2, Wp_loc, bp_loc, Wp_scale, bp_scale,
            Wt_loc, bt_loc, W_ih, W_hh, b_ih, b_hh, out);
    }
}

// Round 2
// 34919.696 us; speedup vs baseline: 2.1131x; 2.1131x over previous
//
#include <hip/hip_runtime.h>
#include <hip/hip_bf16.h>

typedef unsigned short ushort_t;
typedef unsigned int uint_t;

#define BN 512
#define LN 1024
#define FN 38
#define HN 256
#define ZDN 4
#define FXN 64
#define FZN 32
#define HZN 16

constexpr int BT = 2;            // batch rows per workgroup
constexpr int NWG = BN / BT;     // 256 workgroups == #CUs
constexpr int NT = 512;          // threads per workgroup (8 waves -> 2/SIMD)

__device__ __forceinline__ ushort_t f2bf(float f) {
    uint_t u = __float_as_uint(f);
    u += 0x7fffu + ((u >> 16) & 1u);          // round-to-nearest-even
    return (ushort_t)(u >> 16);
}
__device__ __forceinline__ float bflo(uint_t u) { return __uint_as_float(u << 16); }
__device__ __forceinline__ float bfhi(uint_t u) { return __uint_as_float(u & 0xffff0000u); }

__device__ __forceinline__ float sigmoidf_(float v) { return 1.0f / (1.0f + expf(-v)); }
__device__ __forceinline__ float softplusf_(float v) {
    return fmaxf(v, 0.0f) + log1pf(expf(-fabsf(v)));
}

// 8 bf16 weights (packed in uint4) x 8 activations, accumulated for 2 batch rows.
__device__ __forceinline__ void acc8(uint4 w, float4 a0, float4 a1, float4 b0, float4 b1,
                                     float& s0, float& s1) {
    float w0 = bflo(w.x), w1 = bfhi(w.x), w2 = bflo(w.y), w3 = bfhi(w.y);
    float w4 = bflo(w.z), w5 = bfhi(w.z), w6 = bflo(w.w), w7 = bfhi(w.w);
    s0 += w0*a0.x + w1*a0.y + w2*a0.z + w3*a0.w + w4*a1.x + w5*a1.y + w6*a1.z + w7*a1.w;
    s1 += w0*b0.x + w1*b0.y + w2*b0.z + w3*b0.w + w4*b1.x + w5*b1.y + w6*b1.z + w7*b1.w;
}

// Repack W[768][K] f32 -> bf16 [gate][K/8 chunk][256 rows][8], so that a wave
// (64 consecutive j) loading one chunk reads 1 KB contiguous.
template <int K>
__global__ __launch_bounds__(256) void repack_w(const float* __restrict__ W,
                                                ushort_t* __restrict__ dst) {
    int idx = blockIdx.x * 256 + threadIdx.x;
    if (idx >= 768 * K) return;
    int r = idx / K, k = idx % K;
    int g = r >> 8, j = r & 255;
    dst[(((g * (K >> 3) + (k >> 3)) << 8) + j) * 8 + (k & 7)] = f2bf(W[idx]);
}

// fx = relu(x @ Wx^T + bx) for all (b,l), stored bf16 [B][L][64].
__global__ __launch_bounds__(256) void fx_pre(const float* __restrict__ x,
                                              const float* __restrict__ Wx,
                                              const float* __restrict__ bx,
                                              ushort_t* __restrict__ fxbuf) {
    __shared__ float w[FXN][FN + 1];
    __shared__ float bxs[FXN];
    int t = threadIdx.x;
    for (int i = t; i < FXN * FN; i += 256) w[i / FN][i % FN] = Wx[i];
    if (t < FXN) bxs[t] = bx[t];
    __syncthreads();
    size_t id = (size_t)blockIdx.x * 256 + t;     // (b*L + l)
    const float* xr = x + id * FN;
    float xv[FN];
#pragma unroll
    for (int f = 0; f < FN; ++f) xv[f] = xr[f];
    uint4* dst = (uint4*)(fxbuf + id * FXN);
#pragma unroll
    for (int e8 = 0; e8 < 8; ++e8) {
        float a[8];
#pragma unroll
        for (int u = 0; u < 8; ++u) {
            int e = e8 * 8 + u;
            float acc = bxs[e];
#pragma unroll
            for (int f = 0; f < FN; ++f) acc += xv[f] * w[e][f];
            a[u] = fmaxf(acc, 0.0f);
        }
        uint4 o;
        o.x = (uint_t)f2bf(a[0]) | ((uint_t)f2bf(a[1]) << 16);
        o.y = (uint_t)f2bf(a[2]) | ((uint_t)f2bf(a[3]) << 16);
        o.z = (uint_t)f2bf(a[4]) | ((uint_t)f2bf(a[5]) << 16);
        o.w = (uint_t)f2bf(a[6]) | ((uint_t)f2bf(a[7]) << 16);
        dst[e8] = o;
    }
}

template <bool FXPRE>
__global__ __launch_bounds__(NT, 2) void vrnn_main(
    const float* __restrict__ x, const float* __restrict__ eps,
    const float* __restrict__ Wx, const float* __restrict__ bx,
    const float* __restrict__ Wz1, const float* __restrict__ bz1,
    const float* __restrict__ Wz2, const float* __restrict__ bz2,
    const float* __restrict__ Wp_loc, const float* __restrict__ bp_loc,
    const float* __restrict__ Wp_scale, const float* __restrict__ bp_scale,
    const float* __restrict__ Wt_loc, const float* __restrict__ bt_loc,
    const float* __restrict__ b_ih, const float* __restrict__ b_hh,
    const ushort_t* __restrict__ Wihp, const ushort_t* __restrict__ Whhp,
    const ushort_t* __restrict__ fxbuf,
    float* __restrict__ out)
{
    // act = [ h(256) | fx(64) | fz(32) ] per batch row -- matches Wp columns
    // (cat(h,fx)), W_ih columns (cat(fx,fz)), Wt columns (cat(fz,h)).
    __shared__ __attribute__((aligned(16))) float act[BT][352];
    __shared__ float pp[BT][8][16];          // phi partials
    __shared__ float zb[BT][ZDN];
    __shared__ float f1s[BT][HZN];
    __shared__ float pr[2][4][BT][HN];       // GRU partials [khalf][g][m][j]
    __shared__ float epsb[BT][ZDN];
    __shared__ float bsr[HN], bsz[HN], bin_[HN], bhn_[HN];
    __shared__ __attribute__((aligned(16))) float wp[8][320];       // loc rows 0-3, scale 4-7
    __shared__ __attribute__((aligned(16))) ushort_t wtl[FN * 288]; // theta weights bf16
    __shared__ float wz1s[HZN][ZDN], wz2s[FZN][HZN];
    __shared__ float bz1s[HZN], bz2s[FZN], btls[FN], bpls[ZDN], bpss[ZDN];

    const int t = threadIdx.x;
    const int b0 = blockIdx.x * BT;

    // ---- one-time init: small weights -> LDS, fused biases, h=0
    for (int i = t; i < 8 * 320; i += NT)
        wp[i / 320][i % 320] = (i < 1280) ? Wp_loc[i] : Wp_scale[i - 1280];
    for (int i = t; i < FN * 288; i += NT) wtl[i] = f2bf(Wt_loc[i]);
    if (t < HN) {
        bsr[t] = b_ih[t] + b_hh[t];
        bsz[t] = b_ih[HN + t] + b_hh[HN + t];
        bin_[t] = b_ih[2 * HN + t];
        bhn_[t] = b_hh[2 * HN + t];
    }
    if (t < HZN * ZDN) wz1s[t / ZDN][t % ZDN] = Wz1[t];
    for (int i = t; i < FZN * HZN; i += NT) wz2s[i / HZN][i % HZN] = Wz2[i];
    if (t < HZN) bz1s[t] = bz1[t];
    if (t < FZN) bz2s[t] = bz2[t];
    if (t < FN) btls[t] = bt_loc[t];
    if (t < ZDN) { bpls[t] = bp_loc[t]; bpss[t] = bp_scale[t]; }
    for (int i = t; i < BT * HN; i += NT) act[i / HN][i % HN] = 0.0f;

    // prefill l=0 eps and (tier A) fx
    if (t >= 448 && t < 456) {
        int m = (t >> 2) & 1, c = t & 3;
        epsb[m][c] = eps[(size_t)(b0 + m) * ZDN + c];
    }
    if (FXPRE && t >= 480 && t < 496) {
        int m = (t >> 3) & 1, part = t & 7;
        uint4 v = *(const uint4*)(fxbuf + ((size_t)(b0 + m) * LN) * FXN + part * 8);
        float* d = &act[m][HN + part * 8];
        d[0] = bflo(v.x); d[1] = bfhi(v.x); d[2] = bflo(v.y); d[3] = bfhi(v.y);
        d[4] = bflo(v.z); d[5] = bfhi(v.z); d[6] = bflo(v.w); d[7] = bfhi(v.w);
    }
    __syncthreads();

    const int j = t & 255;
    const int sh = t >> 8;   // k-half for GRU split

#pragma unroll 1
    for (int l = 0; l < LN; ++l) {
        // ---- A (tier B only): fx in-loop from global x
        if (!FXPRE) {
            if (t < BT * FXN) {
                int m = t >> 6, e = t & 63;
                const float* xr = x + ((size_t)(b0 + m) * LN + l) * FN;
                const float* wr = Wx + e * FN;
                float acc = bx[e];
#pragma unroll
                for (int f = 0; f < FN; ++f) acc += xr[f] * wr[f];
                act[m][HN + e] = fmaxf(acc, 0.0f);
            }
            __syncthreads();
        }

        // ---- B: phi partials, 256 threads = (m, out c, k-slice ks of 20)
        if (t < 256) {
            int m = t >> 7, r = t & 127, c = r >> 4, ks = r & 15;
            const float4* wv = (const float4*)&wp[c][ks * 20];
            const float4* av = (const float4*)&act[m][ks * 20];
            float acc = 0.0f;
#pragma unroll
            for (int i = 0; i < 5; ++i) {
                float4 w4 = wv[i], a4 = av[i];
                acc += w4.x * a4.x + w4.y * a4.y + w4.z * a4.z + w4.w * a4.w;
            }
            pp[m][c][ks] = acc;
        }
        __syncthreads();

        // ---- C: z = loc + softplus(scale)*eps
        if (t < 8) {
            int m = t >> 2, c = t & 3;
            float lo = bpls[c], sc = bpss[c];
#pragma unroll
            for (int ks = 0; ks < 16; ++ks) { lo += pp[m][c][ks]; sc += pp[m][c + 4][ks]; }
            zb[m][c] = lo + softplusf_(sc) * epsb[m][c];
        }
        __syncthreads();

        // ---- D: f1 = relu(z @ Wz1^T + bz1)
        if (t < BT * HZN) {
            int m = t >> 4, q = t & 15;
            float acc = bz1s[q];
#pragma unroll
            for (int k = 0; k < ZDN; ++k) acc += zb[m][k] * wz1s[q][k];
            f1s[m][q] = fmaxf(acc, 0.0f);
        }
        __syncthreads();

        // ---- E: fz = relu(f1 @ Wz2^T + bz2) -> act[.., 320:352]
        if (t < BT * FZN) {
            int m = t >> 5, q = t & 31;
            float acc = bz2s[q];
#pragma unroll
            for (int k = 0; k < HZN; ++k) acc += f1s[m][k] * wz2s[q][k];
            act[m][HN + FXN + q] = fmaxf(acc, 0.0f);
        }
        __syncthreads();

        // ---- F: prefetch next-step inputs; theta -> out; GRU partial dots
        float pf_eps = 0.0f;
        uint4 pf_fx = {0, 0, 0, 0};
        {
            int lp = (l + 1 < LN) ? l + 1 : LN - 1;
            if (t >= 448 && t < 456) {
                int m = (t >> 2) & 1, c = t & 3;
                pf_eps = eps[((size_t)lp * BN + b0 + m) * ZDN + c];
            }
            if (FXPRE && t >= 480 && t < 496) {
                int m = (t >> 3) & 1, part = t & 7;
                pf_fx = *(const uint4*)(fxbuf + ((size_t)(b0 + m) * LN + lp) * FXN + part * 8);
            }
        }

        if (t < 304) {  // theta: 76 outputs x 4-way k-split, shfl-quad reduce
            int o = t >> 2, s = t & 3;
            int f = o >> 1, m = o & 1;
            int k0 = s * 72;
            float acc = 0.0f;
#pragma unroll
            for (int i = 0; i < 9; ++i) {
                int base = k0 + i * 8;
                uint4 w4 = *(const uint4*)(wtl + f * 288 + base);
                const float* ap = (base < FZN) ? &act[m][HN + FXN + base] : &act[m][base - FZN];
                float4 a0 = *(const float4*)ap;
                float4 a1 = *(const float4*)(ap + 4);
                acc += bflo(w4.x) * a0.x + bfhi(w4.x) * a0.y + bflo(w4.y) * a0.z + bfhi(w4.y) * a0.w;
                acc += bflo(w4.z) * a1.x + bfhi(w4.z) * a1.y + bflo(w4.w) * a1.z + bfhi(w4.w) * a1.w;
            }
            acc += __shfl_xor(acc, 1);
            acc += __shfl_xor(acc, 2);
            if (s == 0) out[((size_t)(b0 + m) * LN + l) * FN + f] = acc + btls[f];
        }

        {   // GRU: thread (j, sh) computes its k-half of r,z,i_n,h_n for row j
            float ar0 = 0, ar1 = 0, az0 = 0, az1 = 0, ain0 = 0, ain1 = 0, ahn0 = 0, ahn1 = 0;
            const ushort_t* wib = Wihp + j * 8;
            const ushort_t* whb = Whhp + j * 8;
            // input part: k in [sh*48, sh*48+48) over act[256:352]
#pragma unroll
            for (int cc = 0; cc < 6; ++cc) {
                int c = sh * 6 + cc;
                const float4* ap0 = (const float4*)&act[0][HN + c * 8];
                const float4* ap1 = (const float4*)&act[1][HN + c * 8];
                float4 a00 = ap0[0], a01 = ap0[1], a10 = ap1[0], a11 = ap1[1];
                uint4 w0 = *(const uint4*)(wib + (0 * 12 + c) * 2048);
                uint4 w1 = *(const uint4*)(wib + (1 * 12 + c) * 2048);
                uint4 w2 = *(const uint4*)(wib + (2 * 12 + c) * 2048);
                acc8(w0, a00, a01, a10, a11, ar0, ar1);
                acc8(w1, a00, a01, a10, a11, az0, az1);
                acc8(w2, a00, a01, a10, a11, ain0, ain1);
            }
            // hidden part: k in [sh*128, sh*128+128) over act[0:256]
#pragma unroll 4
            for (int cc = 0; cc < 16; ++cc) {
                int c = sh * 16 + cc;
                const float4* ap0 = (const float4*)&act[0][c * 8];
                const float4* ap1 = (const float4*)&act[1][c * 8];
                float4 a00 = ap0[0], a01 = ap0[1], a10 = ap1[0], a11 = ap1[1];
                uint4 w0 = *(const uint4*)(whb + (0 * 32 + c) * 2048);
                uint4 w1 = *(const uint4*)(whb + (1 * 32 + c) * 2048);
                uint4 w2 = *(const uint4*)(whb + (2 * 32 + c) * 2048);
                acc8(w0, a00, a01, a10, a11, ar0, ar1);
                acc8(w1, a00, a01, a10, a11, az0, az1);
                acc8(w2, a00, a01, a10, a11, ahn0, ahn1);
            }
            pr[sh][0][0][j] = ar0;  pr[sh][0][1][j] = ar1;
            pr[sh][1][0][j] = az0;  pr[sh][1][1][j] = az1;
            pr[sh][2][0][j] = ain0; pr[sh][2][1][j] = ain1;
            pr[sh][3][0][j] = ahn0; pr[sh][3][1][j] = ahn1;
        }
        __syncthreads();

        // ---- G: combine halves, gates, h update; park prefetched fx/eps
        if (t < 256) {
#pragma unroll
            for (int m = 0; m < BT; ++m) {
                float gr  = pr[0][0][m][j] + pr[1][0][m][j] + bsr[j];
                float gz  = pr[0][1][m][j] + pr[1][1][m][j] + bsz[j];
                float gin = pr[0][2][m][j] + pr[1][2][m][j] + bin_[j];
                float ghn = pr[0][3][m][j] + pr[1][3][m][j] + bhn_[j];
                float r_ = sigmoidf_(gr), z_ = sigmoidf_(gz);
                float n_ = tanhf(gin + r_ * ghn);
                float ho = act[m][j];
                act[m][j] = (1.0f - z_) * n_ + z_ * ho;
            }
        }
        if (t >= 448 && t < 456) { int m = (t >> 2) & 1, c = t & 3; epsb[m][c] = pf_eps; }
        if (FXPRE && t >= 480 && t < 496) {
            int m = (t >> 3) & 1, part = t & 7;
            float* d = &act[m][HN + part * 8];
            d[0] = bflo(pf_fx.x); d[1] = bfhi(pf_fx.x); d[2] = bflo(pf_fx.y); d[3] = bfhi(pf_fx.y);
            d[4] = bflo(pf_fx.z); d[5] = bfhi(pf_fx.z); d[6] = bflo(pf_fx.w); d[7] = bfhi(pf_fx.w);
        }
        __syncthreads();
    }
}

extern "C" void kernel_launch(void* const* d_in, const int* in_sizes, int n_in,
                              void* d_out, int out_size, void* d_ws, size_t ws_size,
                              hipStream_t stream) {
    const float* x        = (const float*)d_in[0];
    const float* eps      = (const float*)d_in[1];
    const float* Wx       = (const float*)d_in[2];
    const float* bx       = (const float*)d_in[3];
    const float* Wz1      = (const float*)d_in[4];
    const float* bz1      = (const float*)d_in[5];
    const float* Wz2      = (const float*)d_in[6];
    const float* bz2      = (const float*)d_in[7];
    const float* Wp_loc   = (const float*)d_in[8];
    const float* bp_loc   = (const float*)d_in[9];
    const float* Wp_scale = (const float*)d_in[10];
    const float* bp_scale = (const float*)d_in[11];
    const float* Wt_loc   = (const float*)d_in[12];
    const float* bt_loc   = (const float*)d_in[13];
    const float* W_ih     = (const float*)d_in[16];
    const float* W_hh     = (const float*)d_in[17];
    const float* b_ih     = (const float*)d_in[18];
    const float* b_hh     = (const float*)d_in[19];
    float* out = (float*)d_out;

    const size_t nIhp = 3 * 256 * (FXN + FZN);   // 73728
    const size_t nHhp = 3 * 256 * HN;            // 196608
    const size_t wneed = (nIhp + nHhp) * sizeof(ushort_t);          // 540672
    const size_t fxneed = (size_t)BN * LN * FXN * sizeof(ushort_t); // 64 MiB

    ushort_t* Wihp  = (ushort_t*)d_ws;
    ushort_t* Whhp  = Wihp + nIhp;
    ushort_t* fxbuf = Whhp + nHhp;

    repack_w<FXN + FZN><<<(768 * (FXN + FZN) + 255) / 256, 256, 0, stream>>>(W_ih, Wihp);
    repack_w<HN><<<(768 * HN + 255) / 256, 256, 0, stream>>>(W_hh, Whhp);

    if (ws_size >= wneed + fxneed) {
        fx_pre<<<BN * LN / 256, 256, 0, stream>>>(x, Wx, bx, fxbuf);
        vrnn_main<true><<<NWG, NT, 0, stream>>>(
            x, eps, Wx, bx, Wz1, bz1, Wz2, bz2, Wp_loc, bp_loc, Wp_scale, bp_scale,
            Wt_loc, bt_loc, b_ih, b_hh, Wihp, Whhp, fxbuf, out);
    } else {
        vrnn_main<false><<<NWG, NT, 0, stream>>>(
            x, eps, Wx, bx, Wz1, bz1, Wz2, bz2, Wp_loc, bp_loc, Wp_scale, bp_scale,
            Wt_loc, bt_loc, b_ih, b_hh, Wihp, Whhp, (const ushort_t*)nullptr, out);
    }
}

// Round 4
// 31756.973 us; speedup vs baseline: 2.3236x; 1.0996x over previous
//
#include <hip/hip_runtime.h>
#include <hip/hip_fp16.h>

typedef unsigned short ushort_t;
typedef unsigned int uint_t;

#define BN 512
#define LN 1024
#define FN 38
#define HN 256
#define ZDN 4
#define FXN 64
#define FZN 32

// stream layout (chunks of 256 rows x 8 k, 4 KB each, f16):
//   q0 (r):  chunks   0..43   (12 xin + 32 h), rows 0..255 of W_ih/W_hh
//   q1 (z):  chunks  44..87   (12 xin + 32 h), rows 256..511
//   q2 (in): chunks  88..99   (12 xin),        W_ih rows 512..767
//   q3 (hn): chunks 100..131  (32 h),          W_hh rows 512..767
#define NCHUNK 132
#define HN_RES 24   // hn chunks resident in LDS

__device__ __forceinline__ ushort_t f2h(float f) { return __half_as_ushort(__float2half(f)); }
__device__ __forceinline__ float h2f(ushort_t u) { return __half2float(__ushort_as_half(u)); }
__device__ __forceinline__ uint_t pk2(float a, float b) {
    return (uint_t)f2h(a) | ((uint_t)f2h(b) << 16);
}

#if defined(__has_builtin)
#if __has_builtin(__builtin_amdgcn_fdot2)
#define HAVE_FDOT2 1
#endif
#endif

typedef _Float16 hv2 __attribute__((ext_vector_type(2)));

__device__ __forceinline__ float dot2h(uint_t w, uint_t a, float acc) {
#ifdef HAVE_FDOT2
    return __builtin_amdgcn_fdot2(__builtin_bit_cast(hv2, w), __builtin_bit_cast(hv2, a), acc, false);
#else
    return acc + h2f((ushort_t)w) * h2f((ushort_t)a)
               + h2f((ushort_t)(w >> 16)) * h2f((ushort_t)(a >> 16));
#endif
}

__device__ __forceinline__ void dot8(uint4 w, uint4 a0, uint4 a1, float& s0, float& s1) {
    s0 = dot2h(w.x, a0.x, s0); s0 = dot2h(w.y, a0.y, s0);
    s0 = dot2h(w.z, a0.z, s0); s0 = dot2h(w.w, a0.w, s0);
    s1 = dot2h(w.x, a1.x, s1); s1 = dot2h(w.y, a1.y, s1);
    s1 = dot2h(w.z, a1.z, s1); s1 = dot2h(w.w, a1.w, s1);
}

__device__ __forceinline__ float sigmoidf_(float v) { return 1.0f / (1.0f + expf(-v)); }
__device__ __forceinline__ float softplusf_(float v) {
    return fmaxf(v, 0.0f) + log1pf(expf(-fabsf(v)));
}

__global__ __launch_bounds__(256) void repack_streams(const float* __restrict__ W_ih,
                                                      const float* __restrict__ W_hh,
                                                      ushort_t* __restrict__ dst) {
    int idx = blockIdx.x * 256 + threadIdx.x;     // over 132*2048 shorts
    if (idx >= NCHUNK * 2048) return;
    int C = idx >> 11, r = idx & 2047, jj = r >> 3, u = r & 7;
    float v;
    if (C < 88) {                 // r (C<44) or z gate
        int q = C < 44 ? 0 : 1, c = C - q * 44, row = q * 256 + jj;
        v = (c < 12) ? W_ih[row * 96 + c * 8 + u] : W_hh[row * 256 + (c - 12) * 8 + u];
    } else if (C < 100) {         // in gate
        v = W_ih[(512 + jj) * 96 + (C - 88) * 8 + u];
    } else {                      // hn gate
        v = W_hh[(512 + jj) * 256 + (C - 100) * 8 + u];
    }
    dst[idx] = f2h(v);
}

// fx = relu(x @ Wx^T + bx) for all (b,l), stored f16-packed [B][L][64].
__global__ __launch_bounds__(256) void fx_pre(const float* __restrict__ x,
                                              const float* __restrict__ Wx,
                                              const float* __restrict__ bx,
                                              ushort_t* __restrict__ fxbuf) {
    __shared__ float w[FXN][FN + 1];
    __shared__ float bxs[FXN];
    int t = threadIdx.x;
    for (int i = t; i < FXN * FN; i += 256) w[i / FN][i % FN] = Wx[i];
    if (t < FXN) bxs[t] = bx[t];
    __syncthreads();
    size_t id = (size_t)blockIdx.x * 256 + t;     // (b*L + l)
    const float* xr = x + id * FN;
    float xv[FN];
#pragma unroll
    for (int f = 0; f < FN; ++f) xv[f] = xr[f];
    uint4* dst = (uint4*)(fxbuf + id * FXN);
#pragma unroll
    for (int e8 = 0; e8 < 8; ++e8) {
        float a[8];
#pragma unroll
        for (int u = 0; u < 8; ++u) {
            int e = e8 * 8 + u;
            float acc = bxs[e];
#pragma unroll
            for (int f = 0; f < FN; ++f) acc += xv[f] * w[e][f];
            a[u] = fmaxf(acc, 0.0f);
        }
        uint4 o;
        o.x = pk2(a[0], a[1]); o.y = pk2(a[2], a[3]);
        o.z = pk2(a[4], a[5]); o.w = pk2(a[6], a[7]);
        dst[e8] = o;
    }
}

template <bool FXPRE>
__global__ __launch_bounds__(1024, 4) void vrnn_main(
    const float* __restrict__ x, const float* __restrict__ eps,
    const float* __restrict__ Wx, const float* __restrict__ bx,
    const float* __restrict__ Wz1, const float* __restrict__ bz1,
    const float* __restrict__ Wz2, const float* __restrict__ bz2,
    const float* __restrict__ Wp_loc, const float* __restrict__ bp_loc,
    const float* __restrict__ Wp_scale, const float* __restrict__ bp_scale,
    const float* __restrict__ Wt_loc, const float* __restrict__ bt_loc,
    const float* __restrict__ b_ih, const float* __restrict__ b_hh,
    const ushort_t* __restrict__ Wstream, const ushort_t* __restrict__ fxbuf,
    float* __restrict__ out)
{
    // f32 act = [h(256) | fx(64) | fz(32)]; actp = same, f16-packed pairs (176 uints)
    __shared__ __attribute__((aligned(16))) float act[2][352];
    __shared__ __attribute__((aligned(16))) uint_t actp[2][176];
    __shared__ float g[4][2][HN];               // full gate dots [q][m][j]
    __shared__ float pp[2][8][16];              // phi partials
    __shared__ float epsb[2][ZDN];
    __shared__ __attribute__((aligned(16))) float wp[8][320];        // phi weights f32
    __shared__ __attribute__((aligned(16))) uint_t wtl[FN * 144];    // theta weights f16 pairs
    __shared__ __attribute__((aligned(16))) uint_t hnres[HN_RES * 1024]; // resident hn chunks
    __shared__ float bsr[HN], bsz[HN], bin_[HN], bhn_[HN];
    __shared__ float wz1s[16][ZDN], wz2s[FZN][16];
    __shared__ float bz1s[16], bz2s[FZN], btls[FN], bpls[ZDN], bpss[ZDN];

    const int t = threadIdx.x;
    const int b0 = blockIdx.x * 2;
    const uint4* W4 = (const uint4*)Wstream;

    // ---- one-time init
    for (int i = t; i < 8 * 320; i += 1024)
        ((float*)wp)[i] = (i < 1280) ? Wp_loc[i] : Wp_scale[i - 1280];
    for (int i = t; i < FN * 144; i += 1024) wtl[i] = pk2(Wt_loc[2 * i], Wt_loc[2 * i + 1]);
    {
        uint4* hd = (uint4*)hnres;
        for (int i = t; i < HN_RES * 256; i += 1024) hd[i] = W4[100 * 256 + i];
    }
    if (t < HN) {
        bsr[t] = b_ih[t] + b_hh[t];
        bsz[t] = b_ih[HN + t] + b_hh[HN + t];
        bin_[t] = b_ih[2 * HN + t];
        bhn_[t] = b_hh[2 * HN + t];
    }
    if (t < 64) ((float*)wz1s)[t] = Wz1[t];
    if (t >= 512 && t < 1024) ((float*)wz2s)[t - 512] = Wz2[t - 512];
    if (t >= 64 && t < 80) bz1s[t - 64] = bz1[t - 64];
    if (t >= 96 && t < 128) bz2s[t - 96] = bz2[t - 96];
    if (t >= 128 && t < 166) btls[t - 128] = bt_loc[t - 128];
    if (t >= 192 && t < 196) bpls[t - 192] = bp_loc[t - 192];
    if (t >= 224 && t < 228) bpss[t - 224] = bp_scale[t - 224];
    if (t >= 256 && t < 768) act[(t - 256) >> 8][(t - 256) & 255] = 0.0f;
    if (t >= 768 && t < 1024) actp[(t - 768) >> 7][(t - 768) & 127] = 0u;
    // prefill l=0 eps / fx
    if (t >= 32 && t < 40) {
        int m = (t >> 2) & 1, c = t & 3;
        epsb[m][c] = eps[(size_t)(b0 + m) * ZDN + c];
    }
    if (FXPRE && t < 16) {
        int m = t >> 3, part = t & 7;
        uint4 v = *(const uint4*)(fxbuf + ((size_t)(b0 + m) * LN) * FXN + part * 8);
        uint_t* ap = &actp[m][128 + part * 4];
        ap[0] = v.x; ap[1] = v.y; ap[2] = v.z; ap[3] = v.w;
        float* d = &act[m][HN + part * 8];
        d[0] = h2f((ushort_t)v.x); d[1] = h2f((ushort_t)(v.x >> 16));
        d[2] = h2f((ushort_t)v.y); d[3] = h2f((ushort_t)(v.y >> 16));
        d[4] = h2f((ushort_t)v.z); d[5] = h2f((ushort_t)(v.z >> 16));
        d[6] = h2f((ushort_t)v.w); d[7] = h2f((ushort_t)(v.w >> 16));
    }
    __syncthreads();

    const int q = t >> 8, j = t & 255;

#pragma unroll 1
    for (int l = 0; l < LN; ++l) {
        // ---- A (tier B only): fx + eps in-loop
        if (!FXPRE) {
            if (t < 64) {
                int m = t >> 5, e2 = t & 31;
                const float* xr = x + ((size_t)(b0 + m) * LN + l) * FN;
                float a0 = bx[2 * e2], a1 = bx[2 * e2 + 1];
                const float* w0 = Wx + (2 * e2) * FN;
                const float* w1 = w0 + FN;
#pragma unroll
                for (int f = 0; f < FN; ++f) { float xv = xr[f]; a0 += xv * w0[f]; a1 += xv * w1[f]; }
                a0 = fmaxf(a0, 0.0f); a1 = fmaxf(a1, 0.0f);
                act[m][HN + 2 * e2] = a0; act[m][HN + 2 * e2 + 1] = a1;
                actp[m][128 + e2] = pk2(a0, a1);
            }
            if (t >= 64 && t < 72) {
                int m = (t >> 2) & 1, c = t & 3;
                epsb[m][c] = eps[((size_t)l * BN + b0 + m) * ZDN + c];
            }
            __syncthreads();
        }

        // ---- B: phi partials (256 threads: m, out c, k-slice of 20)
        if (t < 256) {
            int m = t >> 7, r = t & 127, c = r >> 4, ks = r & 15;
            const float4* wv = (const float4*)&wp[c][ks * 20];
            const float4* av = (const float4*)&act[m][ks * 20];
            float acc = 0.0f;
#pragma unroll
            for (int i = 0; i < 5; ++i) {
                float4 w4 = wv[i], a4 = av[i];
                acc += w4.x * a4.x + w4.y * a4.y + w4.z * a4.z + w4.w * a4.w;
            }
            pp[m][c][ks] = acc;
        }
        __syncthreads();

        // ---- CDE fused (64 threads): z -> f1 -> fz (z/f1 redundant per row)
        if (t < 64) {
            int m = t >> 5, qq = t & 31;
            float zz[ZDN];
#pragma unroll
            for (int c = 0; c < ZDN; ++c) {
                float lo = bpls[c], sc = bpss[c];
#pragma unroll
                for (int ks = 0; ks < 16; ++ks) { lo += pp[m][c][ks]; sc += pp[m][c + 4][ks]; }
                zz[c] = lo + softplusf_(sc) * epsb[m][c];
            }
            float f1v[16];
#pragma unroll
            for (int k = 0; k < 16; ++k) {
                float a = bz1s[k];
#pragma unroll
                for (int c = 0; c < ZDN; ++c) a += zz[c] * wz1s[k][c];
                f1v[k] = fmaxf(a, 0.0f);
            }
            float acc = bz2s[qq];
#pragma unroll
            for (int k = 0; k < 16; ++k) acc += f1v[k] * wz2s[qq][k];
            float v = fmaxf(acc, 0.0f);
            act[m][HN + FXN + qq] = v;
            float oth = __shfl_xor(v, 1);
            if (!(qq & 1)) actp[m][160 + (qq >> 1)] = pk2(v, oth);
        }
        __syncthreads();

        // ---- F: gate dots (all threads) + theta + next-step prefetch
        const uint4* a0p = (const uint4*)actp[0];
        const uint4* a1p = (const uint4*)actp[1];
        float s0 = 0.0f, s1 = 0.0f;
        float pf_eps = 0.0f;
        uint4 pf_fx = {0, 0, 0, 0};
        if (FXPRE) {
            int lp = (l + 1 < LN) ? l + 1 : LN - 1;
            if (t >= 672 && t < 680) {
                int m = (t >> 2) & 1, c = t & 3;
                pf_eps = eps[((size_t)lp * BN + b0 + m) * ZDN + c];
            }
            if (t >= 688 && t < 704) {
                int m = (t >> 3) & 1, part = t & 7;
                pf_fx = *(const uint4*)(fxbuf + ((size_t)(b0 + m) * LN + lp) * FXN + part * 8);
            }
        }

        if (q < 2) {                       // r / z gates: 12 xin + 32 h chunks
            const uint4* wq = W4 + (q ? 44 : 0) * 256 + j;
            uint4 w = wq[0];
#pragma unroll
            for (int c = 0; c < 12; ++c) {
                uint4 wn = wq[(c + 1) * 256];
                dot8(w, a0p[32 + c], a1p[32 + c], s0, s1);
                w = wn;
            }
            uint4 w2 = wq[13 * 256];       // w = chunk 12 (h chunk 0)
#pragma unroll
            for (int c = 0; c < 32; c += 2) {
                uint4 wn1 = (c + 2 < 32) ? wq[(14 + c) * 256] : w;
                uint4 wn2 = (c + 3 < 32) ? wq[(15 + c) * 256] : w2;
                dot8(w, a0p[c], a1p[c], s0, s1);
                dot8(w2, a0p[c + 1], a1p[c + 1], s0, s1);
                w = wn1; w2 = wn2;
            }
        } else if (q == 2) {               // in gate: 12 xin chunks
            const uint4* wq = W4 + 88 * 256 + j;
            uint4 w = wq[0], w2 = wq[256];
#pragma unroll
            for (int c = 0; c < 12; c += 2) {
                uint4 wn1 = (c + 2 < 12) ? wq[(c + 2) * 256] : w;
                uint4 wn2 = (c + 3 < 12) ? wq[(c + 3) * 256] : w2;
                dot8(w, a0p[32 + c], a1p[32 + c], s0, s1);
                dot8(w2, a0p[33 + c], a1p[33 + c], s0, s1);
                w = wn1; w2 = wn2;
            }
            int tt = t - 512;              // theta: 152 threads, 2-way k-split
            if (tt < 152) {
                int o = tt >> 1, s2 = tt & 1, f = o >> 1, m = o & 1;
                const uint4* wt4 = (const uint4*)(wtl + f * 144);
                const uint4* ap = m ? a1p : a0p;
                float acc = 0.0f;
                // 288 k total = 36 uint4; each half covers 18 uint4.
#pragma unroll
                for (int i2 = 0; i2 < 18; ++i2) {
                    int i = s2 * 18 + i2;
                    uint4 wv4 = wt4[i];
                    uint4 av4 = (i < 4) ? ap[40 + i] : ap[i - 4];  // fz | h
                    acc = dot2h(wv4.x, av4.x, acc); acc = dot2h(wv4.y, av4.y, acc);
                    acc = dot2h(wv4.z, av4.z, acc); acc = dot2h(wv4.w, av4.w, acc);
                }
                acc += __shfl_xor(acc, 1);
                if (!s2)
                    __builtin_nontemporal_store(acc + btls[f],
                        &out[((size_t)(b0 + m) * LN + l) * FN + f]);
            }
        } else {                           // hn gate: 24 LDS-resident + 8 streamed
            const uint4* hr = (const uint4*)hnres;
#pragma unroll
            for (int c = 0; c < HN_RES; c += 2) {
                dot8(hr[c * 256 + j], a0p[c], a1p[c], s0, s1);
                dot8(hr[(c + 1) * 256 + j], a0p[c + 1], a1p[c + 1], s0, s1);
            }
            const uint4* wq = W4 + (100 + HN_RES) * 256 + j;
            uint4 w = wq[0], w2 = wq[256];
#pragma unroll
            for (int c = 0; c < 32 - HN_RES; c += 2) {
                uint4 wn1 = (c + 2 < 32 - HN_RES) ? wq[(c + 2) * 256] : w;
                uint4 wn2 = (c + 3 < 32 - HN_RES) ? wq[(c + 3) * 256] : w2;
                dot8(w, a0p[HN_RES + c], a1p[HN_RES + c], s0, s1);
                dot8(w2, a0p[HN_RES + c + 1], a1p[HN_RES + c + 1], s0, s1);
                w = wn1; w2 = wn2;
            }
        }
        g[q][0][j] = s0;
        g[q][1][j] = s1;
        __syncthreads();

        // ---- G: gates + h update (pack via shfl); park prefetched eps/fx
        if (t < 256) {
#pragma unroll
            for (int m = 0; m < 2; ++m) {
                float r_ = sigmoidf_(g[0][m][j] + bsr[j]);
                float z_ = sigmoidf_(g[1][m][j] + bsz[j]);
                float n_ = tanhf(g[2][m][j] + bin_[j] + r_ * (g[3][m][j] + bhn_[j]));
                float hn = (1.0f - z_) * n_ + z_ * act[m][j];
                act[m][j] = hn;
                float oth = __shfl_xor(hn, 1);
                if (!(j & 1)) actp[m][j >> 1] = pk2(hn, oth);
            }
        }
        if (FXPRE) {
            if (t >= 672 && t < 680) { int m = (t >> 2) & 1, c = t & 3; epsb[m][c] = pf_eps; }
            if (t >= 688 && t < 704) {
                int m = (t >> 3) & 1, part = t & 7;
                uint_t* ap2 = &actp[m][128 + part * 4];
                ap2[0] = pf_fx.x; ap2[1] = pf_fx.y; ap2[2] = pf_fx.z; ap2[3] = pf_fx.w;
                float* d = &act[m][HN + part * 8];
                d[0] = h2f((ushort_t)pf_fx.x); d[1] = h2f((ushort_t)(pf_fx.x >> 16));
                d[2] = h2f((ushort_t)pf_fx.y); d[3] = h2f((ushort_t)(pf_fx.y >> 16));
                d[4] = h2f((ushort_t)pf_fx.z); d[5] = h2f((ushort_t)(pf_fx.z >> 16));
                d[6] = h2f((ushort_t)pf_fx.w); d[7] = h2f((ushort_t)(pf_fx.w >> 16));
            }
        }
        __syncthreads();
    }
}

extern "C" void kernel_launch(void* const* d_in, const int* in_sizes, int n_in,
                              void* d_out, int out_size, void* d_ws, size_t ws_size,
                              hipStream_t stream) {
    const float* x        = (const float*)d_in[0];
    const float* eps      = (const float*)d_in[1];
    const float* Wx       = (const float*)d_in[2];
    const float* bx       = (const float*)d_in[3];
    const float* Wz1      = (const float*)d_in[4];
    const float* bz1      = (const float*)d_in[5];
    const float* Wz2      = (const float*)d_in[6];
    const float* bz2      = (const float*)d_in[7];
    const float* Wp_loc   = (const float*)d_in[8];
    const float* bp_loc   = (const float*)d_in[9];
    const float* Wp_scale = (const float*)d_in[10];
    const float* bp_scale = (const float*)d_in[11];
    const float* Wt_loc   = (const float*)d_in[12];
    const float* bt_loc   = (const float*)d_in[13];
    const float* W_ih     = (const float*)d_in[16];
    const float* W_hh     = (const float*)d_in[17];
    const float* b_ih     = (const float*)d_in[18];
    const float* b_hh     = (const float*)d_in[19];
    float* out = (float*)d_out;

    const size_t nStream = (size_t)NCHUNK * 2048;                    // shorts
    const size_t fxElems = (size_t)BN * LN * FXN;                    // shorts
    ushort_t* Wstream = (ushort_t*)d_ws;
    ushort_t* fxbuf   = Wstream + nStream;

    repack_streams<<<(int)((nStream + 255) / 256), 256, 0, stream>>>(W_ih, W_hh, Wstream);

    if (ws_size >= (nStream + fxElems) * sizeof(ushort_t)) {
        fx_pre<<<BN * LN / 256, 256, 0, stream>>>(x, Wx, bx, fxbuf);
        vrnn_main<true><<<256, 1024, 0, stream>>>(
            x, eps, Wx, bx, Wz1, bz1, Wz2, bz2, Wp_loc, bp_loc, Wp_scale, bp_scale,
            Wt_loc, bt_loc, b_ih, b_hh, Wstream, fxbuf, out);
    } else {
        vrnn_main<false><<<256, 1024, 0, stream>>>(
            x, eps, Wx, bx, Wz1, bz1, Wz2, bz2, Wp_loc, bp_loc, Wp_scale, bp_scale,
            Wt_loc, bt_loc, b_ih, b_hh, Wstream, (const ushort_t*)nullptr, out);
    }
}

// Round 5
// 9853.240 us; speedup vs baseline: 7.4889x; 3.2230x over previous
//
#include <hip/hip_runtime.h>
#include <hip/hip_fp16.h>

typedef unsigned short ushort_t;
typedef unsigned int uint_t;

#define BN 512
#define LN 1024
#define FN 38
#define HN 256
#define ZDN 4
#define FXN 64
#define FZN 32

#define NT 512
#define NWG 256
#define HNL 24              // hn-gate chunks (8 k each) resident in LDS: k 0..191
#define HNL_STRIDE_U 1028   // padded uint stride per chunk (spreads banks across s)

__device__ __forceinline__ ushort_t f2h(float f) { return __half_as_ushort(__float2half(f)); }
__device__ __forceinline__ float h2f(ushort_t u) { return __half2float(__ushort_as_half(u)); }
__device__ __forceinline__ uint_t pk2(float a, float b) {
    return (uint_t)f2h(a) | ((uint_t)f2h(b) << 16);
}

#if defined(__has_builtin)
#if __has_builtin(__builtin_amdgcn_fdot2)
#define HAVE_FDOT2 1
#endif
#endif

typedef _Float16 hv2 __attribute__((ext_vector_type(2)));

__device__ __forceinline__ float dot2h(uint_t w, uint_t a, float acc) {
#ifdef HAVE_FDOT2
    return __builtin_amdgcn_fdot2(__builtin_bit_cast(hv2, w), __builtin_bit_cast(hv2, a), acc, false);
#else
    return acc + h2f((ushort_t)w) * h2f((ushort_t)a)
               + h2f((ushort_t)(w >> 16)) * h2f((ushort_t)(a >> 16));
#endif
}

__device__ __forceinline__ float sigmoidf_(float v) { return 1.0f / (1.0f + expf(-v)); }
__device__ __forceinline__ float softplusf_(float v) {
    return fmaxf(v, 0.0f) + log1pf(expf(-fabsf(v)));
}

// butterfly: sum 8 k-slice partials (lane bits 0..2) for slots (m,ri); lane keeps (m=s>>2, ri=s&3)
__device__ __forceinline__ float bfly(float a00, float a01, float a02, float a03,
                                      float a10, float a11, float a12, float a13, int s) {
    a00 += __shfl_xor(a00, 4); a01 += __shfl_xor(a01, 4);
    a02 += __shfl_xor(a02, 4); a03 += __shfl_xor(a03, 4);
    a10 += __shfl_xor(a10, 4); a11 += __shfl_xor(a11, 4);
    a12 += __shfl_xor(a12, 4); a13 += __shfl_xor(a13, 4);
    float v0 = (s & 4) ? a10 : a00;
    float v1 = (s & 4) ? a11 : a01;
    float v2 = (s & 4) ? a12 : a02;
    float v3 = (s & 4) ? a13 : a03;
    v0 += __shfl_xor(v0, 2); v1 += __shfl_xor(v1, 2);
    v2 += __shfl_xor(v2, 2); v3 += __shfl_xor(v3, 2);
    float w0 = (s & 2) ? v2 : v0;
    float w1 = (s & 2) ? v3 : v1;
    w0 += __shfl_xor(w0, 1);
    w1 += __shfl_xor(w1, 1);
    return (s & 1) ? w1 : w0;
}

// Per-thread register slab: uint2 unit n for thread t at slab[(n*512 + t)].
// n 0..43: r-gate, ki=n>>2, ri=n&3, k = s*44+ki*4 (act coords, 352-wide cat(h,fx,fz))
// n 44..87: z-gate same; n 88..99: in-gate k96 = s*12+ki*4; n 100..107: hn k = 192+s*8+ki*4
__global__ __launch_bounds__(256) void repack_slab(const float* __restrict__ W_ih,
                                                   const float* __restrict__ W_hh,
                                                   uint_t* __restrict__ slab) {
    int uid = blockIdx.x * 256 + threadIdx.x;
    if (uid >= 108 * 512 * 2) return;
    int e = uid >> 1, hw = uid & 1;
    int n = e >> 9, t = e & 511;
    int jg = t >> 3, s = t & 7;
    int g, ki, ri;
    if (n < 44)       { g = 0; ki = n >> 2;          ri = n & 3; }
    else if (n < 88)  { g = 1; ki = (n - 44) >> 2;   ri = (n - 44) & 3; }
    else if (n < 100) { g = 2; ki = (n - 88) >> 2;   ri = (n - 88) & 3; }
    else              { g = 3; ki = (n - 100) >> 2;  ri = (n - 100) & 3; }
    int j = 4 * jg + ri;
    float v0, v1;
    if (g < 2) {
        int row = g * 256 + j;
        int k0 = s * 44 + ki * 4 + hw * 2;
        v0 = (k0 < 256) ? W_hh[row * 256 + k0] : W_ih[row * 96 + (k0 - 256)];
        v1 = (k0 + 1 < 256) ? W_hh[row * 256 + k0 + 1] : W_ih[row * 96 + (k0 + 1 - 256)];
    } else if (g == 2) {
        int k0 = s * 12 + ki * 4 + hw * 2;
        v0 = W_ih[(512 + j) * 96 + k0];
        v1 = W_ih[(512 + j) * 96 + k0 + 1];
    } else {
        int k0 = 192 + s * 8 + ki * 4 + hw * 2;
        v0 = W_hh[(512 + j) * 256 + k0];
        v1 = W_hh[(512 + j) * 256 + k0 + 1];
    }
    slab[uid] = pk2(v0, v1);
}

// hn-gate low-k weights: hnsrc[c][row][8k] as uints: uid = c*1024 + row*4 + p, k = c*8 + 2p
__global__ __launch_bounds__(256) void repack_hn(const float* __restrict__ W_hh,
                                                 uint_t* __restrict__ hnsrc) {
    int uid = blockIdx.x * 256 + threadIdx.x;
    if (uid >= HNL * 1024) return;
    int c = uid >> 10, rem = uid & 1023;
    int row = rem >> 2, p = rem & 3;
    int k0 = c * 8 + p * 2;
    hnsrc[uid] = pk2(W_hh[(512 + row) * 256 + k0], W_hh[(512 + row) * 256 + k0 + 1]);
}

// fx = relu(x @ Wx^T + bx) for all (b,l), stored f16-packed [B][L][64].
__global__ __launch_bounds__(256) void fx_pre(const float* __restrict__ x,
                                              const float* __restrict__ Wx,
                                              const float* __restrict__ bx,
                                              ushort_t* __restrict__ fxbuf) {
    __shared__ float w[FXN][FN + 1];
    __shared__ float bxs[FXN];
    int t = threadIdx.x;
    for (int i = t; i < FXN * FN; i += 256) w[i / FN][i % FN] = Wx[i];
    if (t < FXN) bxs[t] = bx[t];
    __syncthreads();
    size_t id = (size_t)blockIdx.x * 256 + t;     // (b*L + l)
    const float* xr = x + id * FN;
    float xv[FN];
#pragma unroll
    for (int f = 0; f < FN; ++f) xv[f] = xr[f];
    uint4* dst = (uint4*)(fxbuf + id * FXN);
#pragma unroll
    for (int e8 = 0; e8 < 8; ++e8) {
        float a[8];
#pragma unroll
        for (int u = 0; u < 8; ++u) {
            int e = e8 * 8 + u;
            float acc = bxs[e];
#pragma unroll
            for (int f = 0; f < FN; ++f) acc += xv[f] * w[e][f];
            a[u] = fmaxf(acc, 0.0f);
        }
        uint4 o;
        o.x = pk2(a[0], a[1]); o.y = pk2(a[2], a[3]);
        o.z = pk2(a[4], a[5]); o.w = pk2(a[6], a[7]);
        dst[e8] = o;
    }
}

template <bool FXPRE>
__global__ __launch_bounds__(NT, 2) void vrnn_main(
    const float* __restrict__ x, const float* __restrict__ eps,
    const float* __restrict__ Wx, const float* __restrict__ bx,
    const float* __restrict__ Wz1, const float* __restrict__ bz1,
    const float* __restrict__ Wz2, const float* __restrict__ bz2,
    const float* __restrict__ Wp_loc, const float* __restrict__ bp_loc,
    const float* __restrict__ Wp_scale, const float* __restrict__ bp_scale,
    const float* __restrict__ Wt_loc, const float* __restrict__ bt_loc,
    const float* __restrict__ b_ih, const float* __restrict__ b_hh,
    const uint_t* __restrict__ Wslab, const uint_t* __restrict__ hnsrc,
    const ushort_t* __restrict__ fxbuf,
    float* __restrict__ out)
{
    // double-buffered activations: act f32 [buf][m][h(256)|fx(64)|fz(32)]; actp f16-packed
    __shared__ __attribute__((aligned(16))) float act[2][2][352];
    __shared__ __attribute__((aligned(16))) uint_t actp[2][2][176];
    __shared__ float pp[2][8][16];
    __shared__ float epsb[2][ZDN];
    __shared__ __attribute__((aligned(16))) float wp[8][320];
    __shared__ __attribute__((aligned(16))) uint_t wtl[FN * 144];
    __shared__ __attribute__((aligned(16))) uint_t whnl[HNL * HNL_STRIDE_U];
    __shared__ float bsr[HN], bsz[HN], bin_[HN], bhn_[HN];
    __shared__ float wz1s[16][ZDN], wz2s[FZN][16];
    __shared__ float bz1s[16], bz2s[FZN], btls[FN], bpls[ZDN], bpss[ZDN];

    const int t = threadIdx.x;
    const int b0 = blockIdx.x * 2;
    const int jg = t >> 3, s = t & 7;

    // ---- one-time init of LDS
    for (int i = t; i < 8 * 320; i += NT)
        ((float*)wp)[i] = (i < 1280) ? Wp_loc[i] : Wp_scale[i - 1280];
    for (int i = t; i < FN * 144; i += NT) wtl[i] = pk2(Wt_loc[2 * i], Wt_loc[2 * i + 1]);
    for (int i = t; i < HNL * 1024; i += NT)
        whnl[(i >> 10) * HNL_STRIDE_U + (i & 1023)] = hnsrc[i];
    if (t < HN) {
        bsr[t] = b_ih[t] + b_hh[t];
        bsz[t] = b_ih[HN + t] + b_hh[HN + t];
        bin_[t] = b_ih[2 * HN + t];
        bhn_[t] = b_hh[2 * HN + t];
    }
    if (t < 64) ((float*)wz1s)[t] = Wz1[t];
    for (int i = t; i < FZN * 16; i += NT) ((float*)wz2s)[i] = Wz2[i];
    if (t < 16) bz1s[t] = bz1[t];
    if (t >= 32 && t < 64) bz2s[t - 32] = bz2[t - 32];
    if (t >= 64 && t < 64 + FN) btls[t - 64] = bt_loc[t - 64];
    if (t >= 128 && t < 132) bpls[t - 128] = bp_loc[t - 128];
    if (t >= 160 && t < 164) bpss[t - 160] = bp_scale[t - 160];
    // zero only h-slots of both buffers (fx/fz are written before use)
    for (int i = t; i < 2 * 2 * 256; i += NT)
        act[(i >> 9) & 1][(i >> 8) & 1][i & 255] = 0.0f;
    for (int i = t; i < 2 * 2 * 128; i += NT)
        actp[(i >> 8) & 1][(i >> 7) & 1][i & 127] = 0u;
    // prefill l=0 eps and (FXPRE) fx into buffer 0
    if (t >= 448 && t < 456) {
        int m = (t >> 2) & 1, c = t & 3;
        epsb[m][c] = eps[(size_t)(b0 + m) * ZDN + c];
    }
    if (FXPRE && t >= 480 && t < 496) {
        int m = (t >> 3) & 1, part = t & 7;
        uint4 v = *(const uint4*)(fxbuf + ((size_t)(b0 + m) * LN) * FXN + part * 8);
        uint_t* ap = &actp[0][m][128 + part * 4];
        ap[0] = v.x; ap[1] = v.y; ap[2] = v.z; ap[3] = v.w;
        float* d = &act[0][m][HN + part * 8];
        d[0] = h2f((ushort_t)v.x); d[1] = h2f((ushort_t)(v.x >> 16));
        d[2] = h2f((ushort_t)v.y); d[3] = h2f((ushort_t)(v.y >> 16));
        d[4] = h2f((ushort_t)v.z); d[5] = h2f((ushort_t)(v.z >> 16));
        d[6] = h2f((ushort_t)v.w); d[7] = h2f((ushort_t)(v.w >> 16));
    }

    // ---- persistent register-resident weights (static indexing only!)
    const uint2* Ws2 = (const uint2*)Wslab;
    uint2 wr[44], wz[44], wi[12], wh[8];
#pragma unroll
    for (int n = 0; n < 44; ++n) wr[n] = Ws2[n * 512 + t];
#pragma unroll
    for (int n = 0; n < 44; ++n) wz[n] = Ws2[(44 + n) * 512 + t];
#pragma unroll
    for (int n = 0; n < 12; ++n) wi[n] = Ws2[(88 + n) * 512 + t];
#pragma unroll
    for (int n = 0; n < 8; ++n) wh[n] = Ws2[(100 + n) * 512 + t];
    __syncthreads();

#pragma unroll 1
    for (int l = 0; l < LN; ++l) {
        const int cur = l & 1, nxt = cur ^ 1;

        // ---- A (tier B only): fx + eps in-loop
        if (!FXPRE) {
            if (t < 64) {
                int m = t >> 5, e2 = t & 31;
                const float* xr = x + ((size_t)(b0 + m) * LN + l) * FN;
                float a0 = bx[2 * e2], a1 = bx[2 * e2 + 1];
                const float* w0 = Wx + (2 * e2) * FN;
                const float* w1 = w0 + FN;
#pragma unroll
                for (int f = 0; f < FN; ++f) { float xv = xr[f]; a0 += xv * w0[f]; a1 += xv * w1[f]; }
                a0 = fmaxf(a0, 0.0f); a1 = fmaxf(a1, 0.0f);
                act[cur][m][HN + 2 * e2] = a0; act[cur][m][HN + 2 * e2 + 1] = a1;
                actp[cur][m][128 + e2] = pk2(a0, a1);
            }
            if (t >= 64 && t < 72) {
                int m = (t >> 2) & 1, c = t & 3;
                epsb[m][c] = eps[((size_t)l * BN + b0 + m) * ZDN + c];
            }
            __syncthreads();
        }

        // ---- B: phi partials (256 threads: m, out c, k-slice of 20)
        if (t < 256) {
            int m = t >> 7, r = t & 127, c = r >> 4, ks = r & 15;
            const float4* wv = (const float4*)&wp[c][ks * 20];
            const float4* av = (const float4*)&act[cur][m][ks * 20];
            float acc = 0.0f;
#pragma unroll
            for (int i = 0; i < 5; ++i) {
                float4 w4 = wv[i], a4 = av[i];
                acc += w4.x * a4.x + w4.y * a4.y + w4.z * a4.z + w4.w * a4.w;
            }
            pp[m][c][ks] = acc;
        }
        __syncthreads();

        // ---- CDE (64 threads): z -> f1 -> fz
        if (t < 64) {
            int m = t >> 5, qq = t & 31;
            float zz[ZDN];
#pragma unroll
            for (int c = 0; c < ZDN; ++c) {
                float lo = bpls[c], sc = bpss[c];
#pragma unroll
                for (int ks = 0; ks < 16; ++ks) { lo += pp[m][c][ks]; sc += pp[m][c + 4][ks]; }
                zz[c] = lo + softplusf_(sc) * epsb[m][c];
            }
            float f1v[16];
#pragma unroll
            for (int k = 0; k < 16; ++k) {
                float a = bz1s[k];
#pragma unroll
                for (int c = 0; c < ZDN; ++c) a += zz[c] * wz1s[k][c];
                f1v[k] = fmaxf(a, 0.0f);
            }
            float acc = bz2s[qq];
#pragma unroll
            for (int k = 0; k < 16; ++k) acc += f1v[k] * wz2s[qq][k];
            float v = fmaxf(acc, 0.0f);
            act[cur][m][HN + FXN + qq] = v;
            float oth = __shfl_xor(v, 1);
            if (!(qq & 1)) actp[cur][m][160 + (qq >> 1)] = pk2(v, oth);
        }
        __syncthreads();

        // ---- F: next-step prefetch + GRU dots (register weights) + theta + update
        float pf_eps = 0.0f;
        uint4 pf_fx = {0, 0, 0, 0};
        if (FXPRE) {
            int lp = (l + 1 < LN) ? l + 1 : LN - 1;
            if (t >= 448 && t < 456) {
                int m = (t >> 2) & 1, c = t & 3;
                pf_eps = eps[((size_t)lp * BN + b0 + m) * ZDN + c];
            }
            if (t >= 480 && t < 496) {
                int m = (t >> 3) & 1, part = t & 7;
                pf_fx = *(const uint4*)(fxbuf + ((size_t)(b0 + m) * LN + lp) * FXN + part * 8);
            }
        }

        const uint2* A0 = (const uint2*)actp[cur][0];
        const uint2* A1 = (const uint2*)actp[cur][1];

        // r & z gates (share activation loads): k-slice s covers act k [44s, 44s+44)
        float r00 = 0, r01 = 0, r02 = 0, r03 = 0, r10 = 0, r11 = 0, r12 = 0, r13 = 0;
        float z00 = 0, z01 = 0, z02 = 0, z03 = 0, z10 = 0, z11 = 0, z12 = 0, z13 = 0;
#pragma unroll
        for (int ki = 0; ki < 11; ++ki) {
            uint2 x0 = A0[s * 11 + ki];
            uint2 x1 = A1[s * 11 + ki];
            uint2 wa = wr[4 * ki + 0], wb = wr[4 * ki + 1], wc = wr[4 * ki + 2], wd = wr[4 * ki + 3];
            r00 = dot2h(wa.x, x0.x, r00); r00 = dot2h(wa.y, x0.y, r00);
            r01 = dot2h(wb.x, x0.x, r01); r01 = dot2h(wb.y, x0.y, r01);
            r02 = dot2h(wc.x, x0.x, r02); r02 = dot2h(wc.y, x0.y, r02);
            r03 = dot2h(wd.x, x0.x, r03); r03 = dot2h(wd.y, x0.y, r03);
            r10 = dot2h(wa.x, x1.x, r10); r10 = dot2h(wa.y, x1.y, r10);
            r11 = dot2h(wb.x, x1.x, r11); r11 = dot2h(wb.y, x1.y, r11);
            r12 = dot2h(wc.x, x1.x, r12); r12 = dot2h(wc.y, x1.y, r12);
            r13 = dot2h(wd.x, x1.x, r13); r13 = dot2h(wd.y, x1.y, r13);
            uint2 za = wz[4 * ki + 0], zb = wz[4 * ki + 1], zc = wz[4 * ki + 2], zd = wz[4 * ki + 3];
            z00 = dot2h(za.x, x0.x, z00); z00 = dot2h(za.y, x0.y, z00);
            z01 = dot2h(zb.x, x0.x, z01); z01 = dot2h(zb.y, x0.y, z01);
            z02 = dot2h(zc.x, x0.x, z02); z02 = dot2h(zc.y, x0.y, z02);
            z03 = dot2h(zd.x, x0.x, z03); z03 = dot2h(zd.y, x0.y, z03);
            z10 = dot2h(za.x, x1.x, z10); z10 = dot2h(za.y, x1.y, z10);
            z11 = dot2h(zb.x, x1.x, z11); z11 = dot2h(zb.y, x1.y, z11);
            z12 = dot2h(zc.x, x1.x, z12); z12 = dot2h(zc.y, x1.y, z12);
            z13 = dot2h(zd.x, x1.x, z13); z13 = dot2h(zd.y, x1.y, z13);
        }
        float gr = bfly(r00, r01, r02, r03, r10, r11, r12, r13, s);
        float gzv = bfly(z00, z01, z02, z03, z10, z11, z12, z13, s);

        // in gate: xin k [12s, 12s+12) -> act k 256 + ...
        float i00 = 0, i01 = 0, i02 = 0, i03 = 0, i10 = 0, i11 = 0, i12 = 0, i13 = 0;
#pragma unroll
        for (int ki = 0; ki < 3; ++ki) {
            uint2 x0 = A0[64 + s * 3 + ki];
            uint2 x1 = A1[64 + s * 3 + ki];
            uint2 wa = wi[4 * ki + 0], wb = wi[4 * ki + 1], wc = wi[4 * ki + 2], wd = wi[4 * ki + 3];
            i00 = dot2h(wa.x, x0.x, i00); i00 = dot2h(wa.y, x0.y, i00);
            i01 = dot2h(wb.x, x0.x, i01); i01 = dot2h(wb.y, x0.y, i01);
            i02 = dot2h(wc.x, x0.x, i02); i02 = dot2h(wc.y, x0.y, i02);
            i03 = dot2h(wd.x, x0.x, i03); i03 = dot2h(wd.y, x0.y, i03);
            i10 = dot2h(wa.x, x1.x, i10); i10 = dot2h(wa.y, x1.y, i10);
            i11 = dot2h(wb.x, x1.x, i11); i11 = dot2h(wb.y, x1.y, i11);
            i12 = dot2h(wc.x, x1.x, i12); i12 = dot2h(wc.y, x1.y, i12);
            i13 = dot2h(wd.x, x1.x, i13); i13 = dot2h(wd.y, x1.y, i13);
        }
        float gin = bfly(i00, i01, i02, i03, i10, i11, i12, i13, s);

        // hn gate: reg part k [192+8s, +8), LDS part chunks c = 3s..3s+2 (k 0..191)
        float h00 = 0, h01 = 0, h02 = 0, h03 = 0, h10 = 0, h11 = 0, h12 = 0, h13 = 0;
#pragma unroll
        for (int ki = 0; ki < 2; ++ki) {
            uint2 x0 = A0[48 + s * 2 + ki];
            uint2 x1 = A1[48 + s * 2 + ki];
            uint2 wa = wh[4 * ki + 0], wb = wh[4 * ki + 1], wc = wh[4 * ki + 2], wd = wh[4 * ki + 3];
            h00 = dot2h(wa.x, x0.x, h00); h00 = dot2h(wa.y, x0.y, h00);
            h01 = dot2h(wb.x, x0.x, h01); h01 = dot2h(wb.y, x0.y, h01);
            h02 = dot2h(wc.x, x0.x, h02); h02 = dot2h(wc.y, x0.y, h02);
            h03 = dot2h(wd.x, x0.x, h03); h03 = dot2h(wd.y, x0.y, h03);
            h10 = dot2h(wa.x, x1.x, h10); h10 = dot2h(wa.y, x1.y, h10);
            h11 = dot2h(wb.x, x1.x, h11); h11 = dot2h(wb.y, x1.y, h11);
            h12 = dot2h(wc.x, x1.x, h12); h12 = dot2h(wc.y, x1.y, h12);
            h13 = dot2h(wd.x, x1.x, h13); h13 = dot2h(wd.y, x1.y, h13);
        }
#pragma unroll
        for (int cc = 0; cc < 3; ++cc) {
            int c = 3 * s + cc;
            uint2 x00 = A0[2 * c], x01 = A0[2 * c + 1];
            uint2 x10 = A1[2 * c], x11 = A1[2 * c + 1];
            uint4 w0 = *(const uint4*)&whnl[c * HNL_STRIDE_U + (4 * jg + 0) * 4];
            uint4 w1 = *(const uint4*)&whnl[c * HNL_STRIDE_U + (4 * jg + 1) * 4];
            uint4 w2 = *(const uint4*)&whnl[c * HNL_STRIDE_U + (4 * jg + 2) * 4];
            uint4 w3 = *(const uint4*)&whnl[c * HNL_STRIDE_U + (4 * jg + 3) * 4];
            h00 = dot2h(w0.x, x00.x, h00); h00 = dot2h(w0.y, x00.y, h00);
            h00 = dot2h(w0.z, x01.x, h00); h00 = dot2h(w0.w, x01.y, h00);
            h01 = dot2h(w1.x, x00.x, h01); h01 = dot2h(w1.y, x00.y, h01);
            h01 = dot2h(w1.z, x01.x, h01); h01 = dot2h(w1.w, x01.y, h01);
            h02 = dot2h(w2.x, x00.x, h02); h02 = dot2h(w2.y, x00.y, h02);
            h02 = dot2h(w2.z, x01.x, h02); h02 = dot2h(w2.w, x01.y, h02);
            h03 = dot2h(w3.x, x00.x, h03); h03 = dot2h(w3.y, x00.y, h03);
            h03 = dot2h(w3.z, x01.x, h03); h03 = dot2h(w3.w, x01.y, h03);
            h10 = dot2h(w0.x, x10.x, h10); h10 = dot2h(w0.y, x10.y, h10);
            h10 = dot2h(w0.z, x11.x, h10); h10 = dot2h(w0.w, x11.y, h10);
            h11 = dot2h(w1.x, x10.x, h11); h11 = dot2h(w1.y, x10.y, h11);
            h11 = dot2h(w1.z, x11.x, h11); h11 = dot2h(w1.w, x11.y, h11);
            h12 = dot2h(w2.x, x10.x, h12); h12 = dot2h(w2.y, x10.y, h12);
            h12 = dot2h(w2.z, x11.x, h12); h12 = dot2h(w2.w, x11.y, h12);
            h13 = dot2h(w3.x, x10.x, h13); h13 = dot2h(w3.y, x10.y, h13);
            h13 = dot2h(w3.z, x11.x, h13); h13 = dot2h(w3.w, x11.y, h13);
        }
        float ghn = bfly(h00, h01, h02, h03, h10, h11, h12, h13, s);

        // theta: 76 outputs x 4-way k-split (288 k = 36 uint4)
        if (t < 304) {
            int o = t >> 2, s4 = t & 3, f = o >> 1, m = o & 1;
            const uint4* wt4 = (const uint4*)(wtl + f * 144);
            const uint4* ap = m ? (const uint4*)actp[cur][1] : (const uint4*)actp[cur][0];
            float acc = 0.0f;
#pragma unroll
            for (int i2 = 0; i2 < 9; ++i2) {
                int i = s4 * 9 + i2;
                uint4 wv4 = wt4[i];
                uint4 av4 = (i < 4) ? ap[40 + i] : ap[i - 4];   // fz | h
                acc = dot2h(wv4.x, av4.x, acc); acc = dot2h(wv4.y, av4.y, acc);
                acc = dot2h(wv4.z, av4.z, acc); acc = dot2h(wv4.w, av4.w, acc);
            }
            acc += __shfl_xor(acc, 1);
            acc += __shfl_xor(acc, 2);
            if (s4 == 0) out[((size_t)(b0 + m) * LN + l) * FN + f] = acc + btls[f];
        }

        // G: gates + h update — lane (jg,s) owns (m = s>>2, j = 4jg + (s&3))
        {
            int m = s >> 2, ri = s & 3, j = 4 * jg + ri;
            float r_ = sigmoidf_(gr + bsr[j]);
            float z_ = sigmoidf_(gzv + bsz[j]);
            float n_ = tanhf(gin + bin_[j] + r_ * (ghn + bhn_[j]));
            float hold = act[cur][m][j];
            float hnew = (1.0f - z_) * n_ + z_ * hold;
            act[nxt][m][j] = hnew;
            float hp = __shfl_xor(hnew, 1);
            if (!(ri & 1)) actp[nxt][m][j >> 1] = pk2(hnew, hp);
        }

        // park prefetched eps / fx into next-step buffers
        if (FXPRE) {
            if (t >= 448 && t < 456) { int m = (t >> 2) & 1, c = t & 3; epsb[m][c] = pf_eps; }
            if (t >= 480 && t < 496) {
                int m = (t >> 3) & 1, part = t & 7;
                uint_t* ap2 = &actp[nxt][m][128 + part * 4];
                ap2[0] = pf_fx.x; ap2[1] = pf_fx.y; ap2[2] = pf_fx.z; ap2[3] = pf_fx.w;
                float* d = &act[nxt][m][HN + part * 8];
                d[0] = h2f((ushort_t)pf_fx.x); d[1] = h2f((ushort_t)(pf_fx.x >> 16));
                d[2] = h2f((ushort_t)pf_fx.y); d[3] = h2f((ushort_t)(pf_fx.y >> 16));
                d[4] = h2f((ushort_t)pf_fx.z); d[5] = h2f((ushort_t)(pf_fx.z >> 16));
                d[6] = h2f((ushort_t)pf_fx.w); d[7] = h2f((ushort_t)(pf_fx.w >> 16));
            }
        }
        __syncthreads();
    }
}

extern "C" void kernel_launch(void* const* d_in, const int* in_sizes, int n_in,
                              void* d_out, int out_size, void* d_ws, size_t ws_size,
                              hipStream_t stream) {
    const float* x        = (const float*)d_in[0];
    const float* eps      = (const float*)d_in[1];
    const float* Wx       = (const float*)d_in[2];
    const float* bx       = (const float*)d_in[3];
    const float* Wz1      = (const float*)d_in[4];
    const float* bz1      = (const float*)d_in[5];
    const float* Wz2      = (const float*)d_in[6];
    const float* bz2      = (const float*)d_in[7];
    const float* Wp_loc   = (const float*)d_in[8];
    const float* bp_loc   = (const float*)d_in[9];
    const float* Wp_scale = (const float*)d_in[10];
    const float* bp_scale = (const float*)d_in[11];
    const float* Wt_loc   = (const float*)d_in[12];
    const float* bt_loc   = (const float*)d_in[13];
    const float* W_ih     = (const float*)d_in[16];
    const float* W_hh     = (const float*)d_in[17];
    const float* b_ih     = (const float*)d_in[18];
    const float* b_hh     = (const float*)d_in[19];
    float* out = (float*)d_out;

    const size_t slabU  = 108 * 512 * 2;            // uints
    const size_t hnU    = (size_t)HNL * 1024;       // uints
    const size_t fxS    = (size_t)BN * LN * FXN;    // shorts

    uint_t* Wslab = (uint_t*)d_ws;
    uint_t* hnsrc = Wslab + slabU;
    ushort_t* fxbuf = (ushort_t*)(hnsrc + hnU);

    repack_slab<<<(int)((slabU + 255) / 256), 256, 0, stream>>>(W_ih, W_hh, Wslab);
    repack_hn<<<(int)((hnU + 255) / 256), 256, 0, stream>>>(W_hh, hnsrc);

    if (ws_size >= (slabU + hnU) * 4 + fxS * 2) {
        fx_pre<<<BN * LN / 256, 256, 0, stream>>>(x, Wx, bx, fxbuf);
        vrnn_main<true><<<NWG, NT, 0, stream>>>(
            x, eps, Wx, bx, Wz1, bz1, Wz2, bz2, Wp_loc, bp_loc, Wp_scale, bp_scale,
            Wt_loc, bt_loc, b_ih, b_hh, Wslab, hnsrc, fxbuf, out);
    } else {
        vrnn_main<false><<<NWG, NT, 0, stream>>>(
            x, eps, Wx, bx, Wz1, bz1, Wz2, bz2, Wp_loc, bp_loc, Wp_scale, bp_scale,
            Wt_loc, bt_loc, b_ih, b_hh, Wslab, hnsrc, (const ushort_t*)nullptr, out);
    }
}